// Round 19
// baseline (370.358 us; speedup 1.0000x reference)
//
#include <hip/hip_runtime.h>
#include <hip/hip_bf16.h>
#include <stdint.h>

typedef __hip_bfloat16 bf16_t;
typedef __attribute__((ext_vector_type(8))) __bf16 bf16x8;
typedef __attribute__((ext_vector_type(4))) float f32x4;
typedef __attribute__((ext_vector_type(8))) unsigned short ushort8;
typedef __attribute__((ext_vector_type(2))) unsigned long long u64x2;

#define BM 256
#define BN 256
#define BK 64
#define THREADS 256
#define OPBYTES 32768   // one operand per buf: 256 rows x 128 B
#define BUFBYTES 65536  // A + B
#define LDS_TOTAL 131072

// ---------------- fused quantize: q = rint(v*100)/100, cast to bf16 ----------------
// NT loads (read-once) + NT 16-B stores (write-through, no dirty per-XCD L2
// lines -> replay-safe cross-kernel visibility; validated r18).
__global__ __launch_bounds__(256) void quant2_bf16_kernel(
    const float* __restrict__ x, const float* __restrict__ w,
    bf16_t* __restrict__ q, long axn8, long totn8) {
  long idx = (long)blockIdx.x * blockDim.x + threadIdx.x;
  long stride = (long)gridDim.x * blockDim.x;
  for (long i = idx; i < totn8; i += stride) {
    const float* src = (i < axn8) ? (x + i * 8) : (w + (i - axn8) * 8);
    const f32x4* p = reinterpret_cast<const f32x4*>(src);
    f32x4 v0 = __builtin_nontemporal_load(p);
    f32x4 v1 = __builtin_nontemporal_load(p + 1);
    float vv[8] = {v0[0], v0[1], v0[2], v0[3], v1[0], v1[1], v1[2], v1[3]};
    ushort8 r;
#pragma unroll
    for (int j = 0; j < 8; ++j) {
      float qq = rintf(vv[j] * 100.0f) / 100.0f;  // half-to-even, matches jnp.round
      __hip_bfloat16 h = __float2bfloat16(qq);
      r[j] = __builtin_bit_cast(unsigned short, h);
    }
    u64x2 u = __builtin_bit_cast(u64x2, r);
    u64x2* dst = reinterpret_cast<u64x2*>(q + i * 8);
    __builtin_nontemporal_store(u, dst);
  }
}

// ---------------- fallback ----------------
__global__ void naive_kernel(const float* __restrict__ x, const float* __restrict__ W,
                             const float* __restrict__ b, float* __restrict__ out,
                             int M, int N, int K) {
  int o = blockIdx.x * blockDim.x + threadIdx.x;
  int m = blockIdx.y;
  if (o >= N || m >= M) return;
  float s = 0.f;
  for (int k = 0; k < K; ++k) {
    float qx = rintf(x[(size_t)m * K + k] * 100.f) / 100.f;
    float qw = rintf(W[(size_t)o * K + k] * 100.f) / 100.f;
    s += qx * qw;
  }
  float v = s + b[o];
  __hip_atomic_store(out + (size_t)m * N + o, v, __ATOMIC_RELAXED,
                     __HIP_MEMORY_SCOPE_AGENT);
}

__device__ __forceinline__ void gload_lds16(const bf16_t* g, const char* l) {
  __builtin_amdgcn_global_load_lds(
      (const __attribute__((address_space(1))) unsigned int*)g,
      (__attribute__((address_space(3))) unsigned int*)l, 16, 0, 0);
}

#define BARRIER()                               \
  do {                                          \
    asm volatile("" ::: "memory");              \
    __builtin_amdgcn_s_barrier();               \
    asm volatile("" ::: "memory");              \
  } while (0)
#define VM16() asm volatile("s_waitcnt vmcnt(16)" ::: "memory")
#define VM0() asm volatile("s_waitcnt vmcnt(0)" ::: "memory")

// ---------------- bf16 GEMM, B^T input: C[m][n] = sum_k A[m][k]*B[n][k] + bias[n]
// ROUND 19: 4-WAVE / FAT-TILE variant of the r16 superphase schedule.
// Serial-sum model (survived r6-r17): time/iter = LDS-pipe cy + MFMA cy,
// because fair LDS round-robin keeps all waves' read bursts aligned. The only
// movable term left is LDS-READ VOLUME: with W_M x W_N waves, block reads/tile
// = W_N*32KB (A) + W_M*32KB (B). 2x2 waves (per-wave 128x128 out) gives
// 128 KB/tile vs 192 KB at 2x4 -> 4608 -> 3072 cy/iter predicted.
// Feasible only at 1 wave/SIMD: acc[8][8] f32x4 = 256 VGPR + 32 operand regs
// fits the 512-VGPR budget (no-spill through 450, m08/m24). Per-SIMD MFMA
// work unchanged (1 wave x 256 MFMA = 2 waves x 128).
//
// Superphases per iter (2 K-tiles; structure = r16, replay-validated):
//   A0 = { read b0: B-lo(8) A-lo(8); MMA(0,0); B-hi(8); MMA(0,1); A-hi(8) } BAR
//   B0 = { stage b0<-t2 (16 ld); MMA(1,1); MMA(1,0); VM16 } BAR
//   A1/B1 mirror on buf1 / t3.
// vmcnt ledger (per-thread; STAGE_X call = 4 loads, 4 calls = 16/tile):
//   enter A0: 16 in flight (b1<-t1, staged prev B1). B0: +16 -> 32; VM16
//   retires exactly b1(t1) (needed A1; 1 superphase+ old). B1: +16 -> 32;
//   VM16 retires exactly b0(t2) (needed next A0). Prologue: t0+t1 (32 loads),
//   VM16 retires t0. PEELED last iter: no stages; VM0 in B0.
// WAR: all buf0 reads (except A-hi) consumed before A0's barrier; A-hi's
// in-flight-across-barrier window vs B0's stage DMA is the same timing r16
// validated under repeated replay (ds_read completes ~120cy from issue;
// DMA data arrives 500+cy after post-barrier issue).
// LDS swizzle: 128B rows, stored slot = slot ^ (row&7) (0 conflicts measured
// r2-r18). global_load_lds dest linear; swizzle on the global SOURCE (rule #21).
__global__ __launch_bounds__(THREADS, 1) void gemm_bt_bf16(
    const bf16_t* __restrict__ A,   // [M][K]
    const bf16_t* __restrict__ B,   // [N][K]
    const float* __restrict__ bias, // [N]
    float* __restrict__ C,          // [M][N]
    int M, int N, int K) {
  extern __shared__ char lds[];

  const int tid = threadIdx.x;
  const int lane = tid & 63;
  const int wave = tid >> 6;  // 0..3
  const int wm = wave >> 1;   // 0..1 -> output rows wm*128..+128
  const int wn = wave & 1;    // 0..1 -> output cols wn*128..+128
  const int lr = lane & 15;
  const int lg = lane >> 4;

  // XCD-aware bijective swizzle (nwg % 8 == 0 guaranteed by tiled_ok)
  int nbn = N / BN;
  int nwg = gridDim.x;
  int bid = blockIdx.x;
  int swz = bid;
  if ((nwg & 7) == 0) {
    int cpx = nwg >> 3;
    swz = (bid & 7) * cpx + (bid >> 3);
  }
  const int brow = (swz / nbn) * BM;
  const int bcol = (swz % nbn) * BN;

  // ds_read byte offsets within an operand region (kk=0; kk=1 is ^64)
  int aoffs[8], boffs[8];
#pragma unroll
  for (int m = 0; m < 8; ++m) {
    int r = wm * 128 + m * 16 + lr;
    aoffs[m] = r * 128 + (((lg) ^ (r & 7)) << 4);
  }
#pragma unroll
  for (int n = 0; n < 8; ++n) {
    int r = wn * 128 + n * 16 + lr;
    boffs[n] = r * 128 + (((lg) ^ (r & 7)) << 4);
  }

  f32x4 acc[8][8];
#pragma unroll
  for (int m = 0; m < 8; ++m)
#pragma unroll
    for (int n = 0; n < 8; ++n) acc[m][n] = (f32x4){0.f, 0.f, 0.f, 0.f};

  const int nt = K / BK;

  // One STAGE call = 4 loads/thread (256 thr x 16B x 4 = 16 KB = one
  // 128-row half of an operand region).
  auto STAGE_A = [&](int h, int kt, int q) {
#pragma unroll
    for (int i = 0; i < 4; ++i) {
      int row = h * 128 + i * 32 + (tid >> 3);
      int L = q * BUFBYTES + row * 128 + ((tid & 7) << 4);
      int slot = (tid & 7) ^ (row & 7);
      gload_lds16(A + (size_t)(brow + row) * K + (size_t)kt * 64 + slot * 8,
                  lds + L);
    }
  };
  auto STAGE_B = [&](int h, int kt, int q) {
#pragma unroll
    for (int i = 0; i < 4; ++i) {
      int row = h * 128 + i * 32 + (tid >> 3);
      int L = q * BUFBYTES + OPBYTES + row * 128 + ((tid & 7) << 4);
      int slot = (tid & 7) ^ (row & 7);
      gload_lds16(B + (size_t)(bcol + row) * K + (size_t)kt * 64 + slot * 8,
                  lds + L);
    }
  };

  bf16x8 aq[16], blo[8], bhi[8];  // aq[m*2+kk]; blo = n0..3, bhi = n4..7
  auto READ_A = [&](int q, int mh) {
#pragma unroll
    for (int mm = 0; mm < 4; ++mm) {
      int m = mh * 4 + mm;
      int off = q * BUFBYTES + aoffs[m];
      aq[m * 2 + 0] = *reinterpret_cast<const bf16x8*>(lds + off);
      aq[m * 2 + 1] = *reinterpret_cast<const bf16x8*>(lds + (off ^ 64));
    }
  };
  auto READ_B = [&](int q, int nh, bf16x8* dst) {
#pragma unroll
    for (int nn = 0; nn < 4; ++nn) {
      int off = q * BUFBYTES + OPBYTES + boffs[nh * 4 + nn];
      dst[nn * 2 + 0] = *reinterpret_cast<const bf16x8*>(lds + off);
      dst[nn * 2 + 1] = *reinterpret_cast<const bf16x8*>(lds + (off ^ 64));
    }
  };
  // One quadrant = 32 MFMA; kk-outer -> dependent same-acc MFMAs 16 apart.
  auto MMA = [&](int mh, int nh, const bf16x8* bb) {
    __builtin_amdgcn_s_setprio(1);
#pragma unroll
    for (int kk = 0; kk < 2; ++kk)
#pragma unroll
      for (int mm = 0; mm < 4; ++mm)
#pragma unroll
        for (int nn = 0; nn < 4; ++nn)
          acc[mh * 4 + mm][nh * 4 + nn] = __builtin_amdgcn_mfma_f32_16x16x32_bf16(
              aq[(mh * 4 + mm) * 2 + kk], bb[nn * 2 + kk],
              acc[mh * 4 + mm][nh * 4 + nn], 0, 0, 0);
    __builtin_amdgcn_s_setprio(0);
  };

  // Prologue: both tiles fully staged (32 loads); VM16 retires tile 0.
  STAGE_B(0, 0, 0); STAGE_B(1, 0, 0); STAGE_A(0, 0, 0); STAGE_A(1, 0, 0);
  STAGE_B(0, 1, 1); STAGE_B(1, 1, 1); STAGE_A(0, 1, 1); STAGE_A(1, 1, 1);
  VM16();
  BARRIER();

  const int np = nt >> 1;
  for (int p = 0; p < np - 1; ++p) {
    const int t2 = 2 * p + 2, t3 = 2 * p + 3;
    // superphase A0: all buf0 reads interleaved with the m-lo MFMAs.
    READ_B(0, 0, blo); READ_A(0, 0);
    MMA(0, 0, blo);
    READ_B(0, 1, bhi);
    MMA(0, 1, bhi);
    READ_A(0, 1);
    BARRIER();  // (1) buf0 reads < buf0 stages
    // superphase B0: stage b0<-t2; m-hi MFMAs; VM16 retires b1(t1).
    STAGE_B(0, t2, 0); STAGE_B(1, t2, 0);
    MMA(1, 1, bhi);
    STAGE_A(0, t2, 0); STAGE_A(1, t2, 0);
    MMA(1, 0, blo);
    VM16();
    BARRIER();  // (2) b1(t1) landed < buf1 reads
    // superphase A1: mirror on buf1.
    READ_B(1, 0, blo); READ_A(1, 0);
    MMA(0, 0, blo);
    READ_B(1, 1, bhi);
    MMA(0, 1, bhi);
    READ_A(1, 1);
    BARRIER();  // (3)
    // superphase B1: stage b1<-t3; VM16 retires b0(t2).
    STAGE_B(0, t3, 1); STAGE_B(1, t3, 1);
    MMA(1, 1, bhi);
    STAGE_A(0, t3, 1); STAGE_A(1, t3, 1);
    MMA(1, 0, blo);
    VM16();
    BARRIER();  // (4)
  }

  // Peeled final iteration: no stages; VM0 in B0 (drains carried b1 loads).
  {
    READ_B(0, 0, blo); READ_A(0, 0);
    MMA(0, 0, blo);
    READ_B(0, 1, bhi);
    MMA(0, 1, bhi);
    READ_A(0, 1);
    BARRIER();
    MMA(1, 1, bhi);
    MMA(1, 0, blo);
    VM0();
    BARRIER();
    READ_B(1, 0, blo); READ_A(1, 0);
    MMA(0, 0, blo);
    READ_B(1, 1, bhi);
    MMA(0, 1, bhi);
    READ_A(1, 1);
    BARRIER();
    MMA(1, 1, bhi);
    MMA(1, 0, blo);
  }

  // Epilogue: C/D layout col=lane&15, row=(lane>>4)*4+reg  [m89/m91]
  // Agent-scope stores (replay-safe visibility past per-XCD L2).
  const int cn = lane & 15;
  const int r4 = (lane >> 4) << 2;
#pragma unroll
  for (int n = 0; n < 8; ++n) {
    const int gcol = bcol + wn * 128 + n * 16 + cn;
    const float bv = bias[gcol];
#pragma unroll
    for (int m = 0; m < 8; ++m) {
      const int grow = brow + wm * 128 + m * 16 + r4;
      float* outp = C + (size_t)grow * N + gcol;
#pragma unroll
      for (int j = 0; j < 4; ++j) {
        float v = acc[m][n][j] + bv;
        __hip_atomic_store(outp + (size_t)j * N, v, __ATOMIC_RELAXED,
                           __HIP_MEMORY_SCOPE_AGENT);
      }
    }
  }
}

extern "C" void kernel_launch(void* const* d_in, const int* in_sizes, int n_in,
                              void* d_out, int out_size, void* d_ws, size_t ws_size,
                              hipStream_t stream) {
  const float* x = (const float*)d_in[0];
  const float* W = (const float*)d_in[1];
  const float* b = (const float*)d_in[2];
  float* out = (float*)d_out;

  const int N = in_sizes[2];       // D_OUT
  const int K = in_sizes[1] / N;   // D_IN
  const int M = in_sizes[0] / K;   // B rows

  const size_t needA = (size_t)M * K * sizeof(bf16_t);
  const size_t needB = (size_t)N * K * sizeof(bf16_t);
  const bool tiled_ok = (M % BM == 0) && (N % BN == 0) && (K % (2 * BK) == 0) &&
                        (K / BK >= 4) && (ws_size >= needA + needB);
  if (!tiled_ok) {
    dim3 g((unsigned)((N + 255) / 256), (unsigned)M);
    naive_kernel<<<g, 256, 0, stream>>>(x, W, b, out, M, N, K);
    return;
  }

  bf16_t* qA = (bf16_t*)d_ws;
  bf16_t* qB = qA + (size_t)M * K;
  const long axn8 = (long)M * K / 8;
  const long totn8 = axn8 + (long)N * K / 8;
  quant2_bf16_kernel<<<2048, 256, 0, stream>>>(x, W, qA, axn8, totn8);

  (void)hipFuncSetAttribute((const void*)gemm_bt_bf16,
                            hipFuncAttributeMaxDynamicSharedMemorySize, LDS_TOTAL);

  const int nwg = (M / BM) * (N / BN);
  gemm_bt_bf16<<<nwg, THREADS, LDS_TOTAL, stream>>>(qA, qB, b, out, M, N, K);
}